// Round 8
// baseline (513.941 us; speedup 1.0000x reference)
//
#include <hip/hip_runtime.h>

#define N_NODES 100000
#define N_EDGES 1600000
#define IN_CH 128
#define HID 256
#define OUT_CH 128
#define N_GRAPHS 2048

#define NBUK 391          // ceil(N_NODES / 256)
#define CHUNK 8192        // edges per binning block

typedef __attribute__((ext_vector_type(8))) short bf16x8;
typedef __attribute__((ext_vector_type(4))) float f32x4;
typedef __attribute__((ext_vector_type(2))) float f32x2;

__device__ inline unsigned short f2b(float f) {  // RNE fp32 -> bf16
    unsigned int u = __builtin_bit_cast(unsigned int, f);
    u = (u + 0x7FFF + ((u >> 16) & 1)) >> 16;
    return (unsigned short)u;
}
__device__ inline float b2f(unsigned short h) {
    unsigned int u = (unsigned int)h << 16;
    return __builtin_bit_cast(float, u);
}

// async global->LDS, 16 B per lane; dst is wave-uniform base, HW adds lane*16
#define GLOAD_LDS16(gsrc, ldst)                                                   \
    __builtin_amdgcn_global_load_lds(                                             \
        (const __attribute__((address_space(1))) void*)(gsrc),                    \
        (__attribute__((address_space(3))) void*)(ldst), 16, 0, 0)

// ---------------------------------------------------------------- scan (bucket bases)
// NBUK=391 fits one 256x8 tile; also writes grand total to *total.
#define SCAN_ITEMS 8
#define SCAN_TILE (256 * SCAN_ITEMS)

__global__ void scan1_k(const int* __restrict__ in, int* __restrict__ out,
                        int n, int* __restrict__ total) {
    __shared__ int wsum[4];
    int base = blockIdx.x * SCAN_TILE + (int)threadIdx.x * SCAN_ITEMS;
    int v[SCAN_ITEMS];
    int s = 0;
    #pragma unroll
    for (int i = 0; i < SCAN_ITEMS; ++i) {
        v[i] = (base + i < n) ? in[base + i] : 0;
        s += v[i];
    }
    int lane = threadIdx.x & 63, wid = threadIdx.x >> 6;
    int incl = s;
    #pragma unroll
    for (int off = 1; off < 64; off <<= 1) {
        int t = __shfl_up(incl, off, 64);
        if (lane >= off) incl += t;
    }
    if (lane == 63) wsum[wid] = incl;
    __syncthreads();
    int wprefix = 0;
    #pragma unroll
    for (int w = 0; w < 4; ++w)
        if (w < wid) wprefix += wsum[w];
    int run = wprefix + incl - s;
    #pragma unroll
    for (int i = 0; i < SCAN_ITEMS; ++i) {
        if (base + i < n) out[base + i] = run;
        run += v[i];
    }
    if (threadIdx.x == 255) *total = wprefix + incl;
}

// ---------------------------------------------------------------- bucketed CSR build
__global__ void bucket_count_k(const int* __restrict__ dst, int* __restrict__ bcnt, int E) {
    __shared__ int cnt[NBUK];
    int tid = threadIdx.x;
    for (int i = tid; i < NBUK; i += 256) cnt[i] = 0;
    __syncthreads();
    int e0 = blockIdx.x * CHUNK;
    int eend = min(e0 + CHUNK, E);
    for (int e = e0 + tid; e < eend; e += 256)
        atomicAdd(&cnt[dst[e] >> 8], 1);
    __syncthreads();
    for (int i = tid; i < NBUK; i += 256)
        if (cnt[i]) atomicAdd(&bcnt[i], cnt[i]);
}

// staging entry packs src (17 bits, N<2^17) << 8 | (dst & 255): 4 B instead of 8.
__global__ void bin_scatter_k(const int* __restrict__ src, const int* __restrict__ dst,
                              const int* __restrict__ bbase, int* __restrict__ bcur,
                              unsigned* __restrict__ staging, int E) {
    __shared__ int cnt[NBUK];
    __shared__ int gbase[NBUK];
    int tid = threadIdx.x;
    for (int i = tid; i < NBUK; i += 256) cnt[i] = 0;
    __syncthreads();
    int e0 = blockIdx.x * CHUNK;
    int eend = min(e0 + CHUNK, E);
    for (int e = e0 + tid; e < eend; e += 256)
        atomicAdd(&cnt[dst[e] >> 8], 1);
    __syncthreads();
    for (int i = tid; i < NBUK; i += 256) {
        int c = cnt[i];
        gbase[i] = c ? (bbase[i] + atomicAdd(&bcur[i], c)) : 0;
        cnt[i] = 0;  // reuse as local cursor
    }
    __syncthreads();
    for (int e = e0 + tid; e < eend; e += 256) {
        int d = dst[e];
        int b = d >> 8;
        int l = atomicAdd(&cnt[b], 1);
        staging[(size_t)gbase[b] + l] = ((unsigned)src[e] << 8) | (unsigned)(d & 255);
    }
}

__global__ void csr_build_k(const unsigned* __restrict__ staging, const int* __restrict__ bbase,
                            int* __restrict__ row_ofs, int* __restrict__ csr) {
    __shared__ int ldeg[256];
    __shared__ int lofs[256];
    __shared__ int wsum[4];
    int b = blockIdx.x, tid = threadIdx.x;
    int base = bbase[b];
    int cnt = bbase[b + 1] - base;
    ldeg[tid] = 0;
    __syncthreads();
    const unsigned* sp = staging + base;
    for (int i = tid; i < cnt; i += 256)
        atomicAdd(&ldeg[sp[i] & 255], 1);
    __syncthreads();
    int v = ldeg[tid];
    int lane = tid & 63, wid = tid >> 6;
    int incl = v;
    #pragma unroll
    for (int off = 1; off < 64; off <<= 1) {
        int t = __shfl_up(incl, off, 64);
        if (lane >= off) incl += t;
    }
    if (lane == 63) wsum[wid] = incl;
    __syncthreads();
    int wprefix = 0;
    #pragma unroll
    for (int w = 0; w < 4; ++w)
        if (w < wid) wprefix += wsum[w];
    int excl = wprefix + incl - v;
    lofs[tid] = excl;
    int node = b * 256 + tid;
    if (node < N_NODES) row_ofs[node] = base + excl;
    if (b == NBUK - 1 && tid == 0) row_ofs[N_NODES] = N_EDGES;
    ldeg[tid] = 0;  // reuse as cursor
    __syncthreads();
    for (int i = tid; i < cnt; i += 256) {
        unsigned p = sp[i];
        int d = (int)(p & 255);
        int pos = atomicAdd(&ldeg[d], 1);
        csr[base + lofs[d] + pos] = (int)(p >> 8);
    }
}

// ---------------------------------------------------------------- fused prep
// One launch: W1 concat->bf16 (blocks 0..255), W2 concat->bf16 (256..767),
// x fp32 -> (bf16, fp8) (768..).
__global__ void prep_k(const float* __restrict__ W1l, const float* __restrict__ W1r,
                       unsigned short* __restrict__ W1T,
                       const float* __restrict__ W2l, const float* __restrict__ W2r,
                       unsigned short* __restrict__ W2T,
                       const float* __restrict__ x, unsigned short* __restrict__ xb,
                       unsigned char* __restrict__ x8) {
    int b = blockIdx.x;
    if (b < 256) {                       // W1T: HID*(2*IN_CH) = 65536 elems
        int idx = b * 256 + (int)threadIdx.x;
        const int KT = 2 * IN_CH;
        int n = idx / KT, k = idx % KT;
        float v = (k < IN_CH) ? W1l[(size_t)k * HID + n] : W1r[(size_t)(k - IN_CH) * HID + n];
        W1T[idx] = f2b(v);
    } else if (b < 768) {                // W2T: HID*(2*HID) = 131072 elems
        int idx = (b - 256) * 256 + (int)threadIdx.x;
        const int KT = 2 * HID;
        int n = idx / KT, k = idx % KT;
        float v = (k < HID) ? W2l[(size_t)k * HID + n] : W2r[(size_t)(k - HID) * HID + n];
        W2T[idx] = f2b(v);
    } else {                             // f2b8 over N*IN_CH/8 groups
        size_t i = (size_t)(b - 768) * 256 + threadIdx.x;
        size_t n8 = (size_t)N_NODES * IN_CH / 8;
        if (i >= n8) return;
        float4 a = ((const float4*)x)[i * 2];
        float4 c = ((const float4*)x)[i * 2 + 1];
        unsigned short ob[8];
        ob[0] = f2b(a.x); ob[1] = f2b(a.y); ob[2] = f2b(a.z); ob[3] = f2b(a.w);
        ob[4] = f2b(c.x); ob[5] = f2b(c.y); ob[6] = f2b(c.z); ob[7] = f2b(c.w);
        ((uint4*)xb)[i] = *(const uint4*)ob;
        int w0 = 0, w1 = 0;
        w0 = __builtin_amdgcn_cvt_pk_fp8_f32(a.x, a.y, w0, false);
        w0 = __builtin_amdgcn_cvt_pk_fp8_f32(a.z, a.w, w0, true);
        w1 = __builtin_amdgcn_cvt_pk_fp8_f32(c.x, c.y, w1, false);
        w1 = __builtin_amdgcn_cvt_pk_fp8_f32(c.z, c.w, w1, true);
        uint2 o8; o8.x = (unsigned int)w0; o8.y = (unsigned int)w1;
        ((uint2*)x8)[i] = o8;
    }
}

// ---------------------------------------------------------------- mean aggregation
// R8: fp8 in [n,C] -> bf16 mean out [n,C]. One wave per node.
// Latency restructure, DIVERGENCE-SAFE (R7 post-mortem: per-lane loop bounds with
// __shfl inside read EXEC-inactive source lanes -> garbage indices):
//  - coalesced index preload (one wave-wide csr read covers first 64 edges);
//  - 4-deep main loop with WAVE-UNIFORM bound (st+4)*NG <= nfull: worst-case lane
//    g=NG-1 still has all 4 edges valid -> no predication, no divergence;
//  - remainder loop with uniform bound st*NG < nfull: ALL lanes execute the shfl
//    (source lane st*NG+g <= 63 always; padding lanes hold idx 0), only the
//    gather+accum is predicated (no cross-lane ops inside the guard).
// Per-lane accumulation order identical to R6 (ascending residue class).
// Degree>64 tail reads csr directly (no shfl; divergence harmless).
template <int C>
__global__ void agg_f8_k(const unsigned char* __restrict__ X8, const int* __restrict__ row_ofs,
                         const int* __restrict__ csr, unsigned short* __restrict__ out, int n) {
    constexpr int GL = C / 16;      // lanes per feature row
    constexpr int NG = 64 / GL;     // edge groups per wave
    int w = (int)((blockIdx.x * blockDim.x + threadIdx.x) >> 6);
    int lane = threadIdx.x & 63;
    if (w >= n) return;
    int g = lane / GL, il = lane % GL;
    int s = row_ofs[w], e = row_ofs[w + 1];
    int deg = e - s;
    int myidx = (lane < deg) ? csr[s + lane] : 0;   // coalesced preload
    int nfull = min(deg, 64);

    float a[16];
    #pragma unroll
    for (int t = 0; t < 16; ++t) a[t] = 0.f;

    auto accum = [&](uint4 r) {
        const unsigned int* q = (const unsigned int*)&r;
        #pragma unroll
        for (int t = 0; t < 4; ++t) {
            f32x2 lo = __builtin_amdgcn_cvt_pk_f32_fp8(q[t], false);
            f32x2 hi = __builtin_amdgcn_cvt_pk_f32_fp8(q[t], true);
            a[t * 4 + 0] += lo.x; a[t * 4 + 1] += lo.y;
            a[t * 4 + 2] += hi.x; a[t * 4 + 3] += hi.y;
        }
    };

    int st = 0;
    for (; (st + 4) * NG <= nfull; st += 4) {       // uniform: all 4 valid for all lanes
        int i0 = __shfl(myidx, (st + 0) * NG + g, 64);
        int i1 = __shfl(myidx, (st + 1) * NG + g, 64);
        int i2 = __shfl(myidx, (st + 2) * NG + g, 64);
        int i3 = __shfl(myidx, (st + 3) * NG + g, 64);
        uint4 r0 = *(const uint4*)&X8[(size_t)i0 * C + il * 16];
        uint4 r1 = *(const uint4*)&X8[(size_t)i1 * C + il * 16];
        uint4 r2 = *(const uint4*)&X8[(size_t)i2 * C + il * 16];
        uint4 r3 = *(const uint4*)&X8[(size_t)i3 * C + il * 16];
        accum(r0); accum(r1); accum(r2); accum(r3);
    }
    for (; st * NG < nfull; ++st) {                 // uniform bound; predicated body
        int ed = st * NG + g;                       // <= 63 always
        int i0 = __shfl(myidx, ed, 64);             // all lanes participate
        if (ed < nfull) {
            uint4 r0 = *(const uint4*)&X8[(size_t)i0 * C + il * 16];
            accum(r0);
        }
    }
    for (int j = s + 64 + g; j < e; j += NG) {      // deg>64 tail (no shfl)
        int i0 = csr[j];
        uint4 r0 = *(const uint4*)&X8[(size_t)i0 * C + il * 16];
        accum(r0);
    }

    #pragma unroll
    for (int m = GL; m < 64; m <<= 1)
        #pragma unroll
        for (int t = 0; t < 16; ++t) a[t] += __shfl_xor(a[t], m, 64);

    if (g == 0) {
        float inv = 1.0f / (float)max(e - s, 1);
        uint4 o0, o1;
        unsigned short* p0 = (unsigned short*)&o0;
        unsigned short* p1 = (unsigned short*)&o1;
        #pragma unroll
        for (int t = 0; t < 8; ++t) p0[t] = f2b(a[t] * inv);
        #pragma unroll
        for (int t = 0; t < 8; ++t) p1[t] = f2b(a[8 + t] * inv);
        *(uint4*)&out[(size_t)w * C + il * 16] = o0;
        *(uint4*)&out[(size_t)w * C + il * 16 + 8] = o1;
    }
}

// pool: bf16 input [N,256] -> fp32 pooled [G,256]; one wave per graph.
// Graph bounds via in-wave binary search on batch; row loop unrolled x4.
__global__ void pool_mean_k(const unsigned short* __restrict__ H, const int* __restrict__ batch,
                            float* __restrict__ pooled, int G, int n) {
    int g = (int)((blockIdx.x * blockDim.x + threadIdx.x) >> 6);
    int lane = threadIdx.x & 63;
    if (g >= G) return;
    int lo = 0, hi = n;
    while (lo < hi) { int mid = (lo + hi) >> 1; if (batch[mid] < g) lo = mid + 1; else hi = mid; }
    int s = lo;
    hi = n;
    while (lo < hi) { int mid = (lo + hi) >> 1; if (batch[mid] < g + 1) lo = mid + 1; else hi = mid; }
    int e = lo;

    float a0 = 0.f, a1 = 0.f, a2 = 0.f, a3 = 0.f;
    float b0 = 0.f, b1 = 0.f, b2 = 0.f, b3 = 0.f;
    int r = s;
    for (; r + 4 <= e; r += 4) {
        ushort4 t0 = ((const ushort4*)(H + (size_t)(r + 0) * HID))[lane];
        ushort4 t1 = ((const ushort4*)(H + (size_t)(r + 1) * HID))[lane];
        ushort4 t2 = ((const ushort4*)(H + (size_t)(r + 2) * HID))[lane];
        ushort4 t3 = ((const ushort4*)(H + (size_t)(r + 3) * HID))[lane];
        a0 += b2f(t0.x); a1 += b2f(t0.y); a2 += b2f(t0.z); a3 += b2f(t0.w);
        b0 += b2f(t1.x); b1 += b2f(t1.y); b2 += b2f(t1.z); b3 += b2f(t1.w);
        a0 += b2f(t2.x); a1 += b2f(t2.y); a2 += b2f(t2.z); a3 += b2f(t2.w);
        b0 += b2f(t3.x); b1 += b2f(t3.y); b2 += b2f(t3.z); b3 += b2f(t3.w);
    }
    for (; r < e; ++r) {
        ushort4 t = ((const ushort4*)(H + (size_t)r * HID))[lane];
        a0 += b2f(t.x); a1 += b2f(t.y); a2 += b2f(t.z); a3 += b2f(t.w);
    }
    float inv = 1.0f / (float)max(e - s, 1);
    float4 o; o.x = (a0 + b0) * inv; o.y = (a1 + b1) * inv;
    o.z = (a2 + b2) * inv; o.w = (a3 + b3) * inv;
    ((float4*)(pooled + (size_t)g * HID))[lane] = o;
}

// ---------------------------------------------------------------- bf16 MFMA GEMM
// R1-proven config (fastest passing), FROZEN: 128x128 tile, 4 waves 2x2, BK=32,
// triple-buffered LDS (depth-2 prefetch, steady-state vmcnt(8)), 48 KB LDS.
// R2/R3/R4: bigger tiles, finer interleave, 0-conflict swizzle, fp8 operands all
// neutral-or-worse on this skinny shape (N=256) -- plateau is structural.
__launch_bounds__(256)
__global__ void mfma_gemm_k(const unsigned short* __restrict__ A1, int K1,
                            const unsigned short* __restrict__ A2, int K2,
                            const unsigned short* __restrict__ Bt,
                            const float* __restrict__ bias, int M, int Nfull,
                            void* __restrict__ Cptr, unsigned char* __restrict__ f8out,
                            int c_bf16, int do_relu) {
    __shared__ short ldsA[3 * 4096];
    __shared__ short ldsB[3 * 4096];
    int tid = threadIdx.x, lane = tid & 63;
    int wid = tid >> 6, wm = wid >> 1, wn = wid & 1;
    int row0 = blockIdx.x * 128, col0 = blockIdx.y * 128;
    int q = lane >> 4, l15 = lane & 15;
    int KT = K1 + K2;
    int nk = KT / 32;

    int rr = tid >> 2;                       // 0..63 row within half-tile
    int c8 = ((tid & 3) ^ (rr & 3)) * 8;     // swizzled source k-chunk (shorts)
    int dof = wid * 512;                     // wave-uniform LDS base (shorts) per half

    auto stage = [&](int t, short* bA, short* bB) {
        int kt = t * 32;
        const unsigned short* Asrc; int kk, Ks;
        if (kt < K1) { Asrc = A1; kk = kt; Ks = K1; }
        else         { Asrc = A2; kk = kt - K1; Ks = K2; }
        #pragma unroll
        for (int h = 0; h < 2; ++h) {
            int r = h * 64 + rr;
            int gr = min(row0 + r, M - 1);
            GLOAD_LDS16(Asrc + (size_t)gr * Ks + kk + c8, bA + h * 2048 + dof);
            GLOAD_LDS16(Bt + (size_t)(col0 + r) * KT + kt + c8, bB + h * 2048 + dof);
        }
    };

    f32x4 acc[4][4] = {};

    stage(0, ldsA, ldsB);                    // nk >= 8 always
    stage(1, ldsA + 4096, ldsB + 4096);
    stage(2, ldsA + 8192, ldsB + 8192);

    int bi = 0;
    for (int t = 0; t < nk; ++t) {
        if (t + 2 < nk)      asm volatile("s_waitcnt vmcnt(8)" ::: "memory");
        else if (t + 1 < nk) asm volatile("s_waitcnt vmcnt(4)" ::: "memory");
        else                 asm volatile("s_waitcnt vmcnt(0)" ::: "memory");
        asm volatile("s_barrier" ::: "memory");   // tile t visible to all waves

        short* bA = ldsA + bi * 4096;
        short* bB = ldsB + bi * 4096;
        bf16x8 af[4], bfr[4];
        #pragma unroll
        for (int i = 0; i < 4; ++i) {
            int r = wm * 64 + i * 16 + l15;
            af[i] = *(const bf16x8*)&bA[r * 32 + (q ^ (r & 3)) * 8];
        }
        #pragma unroll
        for (int j = 0; j < 4; ++j) {
            int r = wn * 64 + j * 16 + l15;
            bfr[j] = *(const bf16x8*)&bB[r * 32 + (q ^ (r & 3)) * 8];
        }
        #pragma unroll
        for (int i = 0; i < 4; ++i)
            #pragma unroll
            for (int j = 0; j < 4; ++j)
                acc[i][j] = __builtin_amdgcn_mfma_f32_16x16x32_bf16(af[i], bfr[j], acc[i][j], 0, 0, 0);

        asm volatile("s_barrier" ::: "memory");   // all waves done reading buf bi
        if (t + 3 < nk) stage(t + 3, bA, bB);     // refill buffer just consumed
        bi = (bi == 2) ? 0 : bi + 1;
    }

    // epilogue: D layout col=lane&15, row=quad*4+reg
    #pragma unroll
    for (int i = 0; i < 4; ++i) {
        #pragma unroll
        for (int reg = 0; reg < 4; ++reg) {
            int r = row0 + wm * 64 + i * 16 + q * 4 + reg;
            if (r < M) {
                #pragma unroll
                for (int j = 0; j < 4; ++j) {
                    int cc = col0 + wn * 64 + j * 16 + l15;
                    float v = acc[i][j][reg] + bias[cc];
                    if (do_relu) v = fmaxf(v, 0.f);
                    if (c_bf16) ((unsigned short*)Cptr)[(size_t)r * Nfull + cc] = f2b(v);
                    else        ((float*)Cptr)[(size_t)r * Nfull + cc] = v;
                    if (f8out) {
                        int w8 = __builtin_amdgcn_cvt_pk_fp8_f32(v, v, 0, false);
                        f8out[(size_t)r * Nfull + cc] = (unsigned char)(w8 & 0xFF);
                    }
                }
            }
        }
    }
}

// ---------------------------------------------------------------- fp32 head GEMM
// 32x32 tile per block, 256 thr, each thread a 2x2 micro-tile; K multiple of 16.
__global__ void head_gemm_k(const float* __restrict__ A, const float* __restrict__ B,
                            const float* __restrict__ bias, float* __restrict__ C,
                            int M, int N, int K, int do_relu) {
    __shared__ float As[16][33];
    __shared__ float Bs[16][33];
    int tid = threadIdx.x;
    int row0 = blockIdx.x * 32, col0 = blockIdx.y * 32;
    int tx = tid & 15, ty = tid >> 4;       // 16x16 threads of 2x2 outs
    float a00 = 0.f, a01 = 0.f, a10 = 0.f, a11 = 0.f;

    for (int kt = 0; kt < K; kt += 16) {
        if (tid < 128) {                    // A tile 32x16
            int r = tid >> 2, kc = (tid & 3) * 4;
            float4 v = *(const float4*)(A + (size_t)(row0 + r) * K + kt + kc);
            As[kc + 0][r] = v.x; As[kc + 1][r] = v.y;
            As[kc + 2][r] = v.z; As[kc + 3][r] = v.w;
        } else {                            // B tile 16x32
            int t2 = tid - 128;
            int kr = t2 >> 3, c4 = (t2 & 7) * 4;
            float4 v = *(const float4*)(B + (size_t)(kt + kr) * N + col0 + c4);
            *(float4*)&Bs[kr][c4] = v;
        }
        __syncthreads();
        #pragma unroll
        for (int k = 0; k < 16; ++k) {
            float x0 = As[k][ty * 2], x1 = As[k][ty * 2 + 1];
            float y0 = Bs[k][tx * 2], y1 = Bs[k][tx * 2 + 1];
            a00 = fmaf(x0, y0, a00); a01 = fmaf(x0, y1, a01);
            a10 = fmaf(x1, y0, a10); a11 = fmaf(x1, y1, a11);
        }
        __syncthreads();
    }

    int r0 = row0 + ty * 2, c0 = col0 + tx * 2;
    float bv0 = bias[c0], bv1 = bias[c0 + 1];
    float o00 = a00 + bv0, o01 = a01 + bv1, o10 = a10 + bv0, o11 = a11 + bv1;
    if (do_relu) {
        o00 = fmaxf(o00, 0.f); o01 = fmaxf(o01, 0.f);
        o10 = fmaxf(o10, 0.f); o11 = fmaxf(o11, 0.f);
    }
    C[(size_t)r0 * N + c0] = o00;       C[(size_t)r0 * N + c0 + 1] = o01;
    C[(size_t)(r0 + 1) * N + c0] = o10; C[(size_t)(r0 + 1) * N + c0 + 1] = o11;
}

// ---------------------------------------------------------------- launcher
extern "C" void kernel_launch(void* const* d_in, const int* in_sizes, int n_in,
                              void* d_out, int out_size, void* d_ws, size_t ws_size,
                              hipStream_t stream) {
    const float* x    = (const float*)d_in[0];
    const int*   ei   = (const int*)d_in[1];
    const int*   batch= (const int*)d_in[2];
    const float* W1l  = (const float*)d_in[3];
    const float* b1   = (const float*)d_in[4];
    const float* W1r  = (const float*)d_in[5];
    const float* W2l  = (const float*)d_in[6];
    const float* b2   = (const float*)d_in[7];
    const float* W2r  = (const float*)d_in[8];
    const float* W3   = (const float*)d_in[9];
    const float* b3   = (const float*)d_in[10];
    const float* W4   = (const float*)d_in[11];
    const float* b4   = (const float*)d_in[12];
    float* out = (float*)d_out;

    const int N = N_NODES, E = N_EDGES, G = N_GRAPHS;
    const int* src = ei;
    const int* dst = ei + E;

    char* ws = (char*)d_ws;
    size_t off = 0;
    auto alloc = [&](size_t bytes) -> char* {
        off = (off + 255) & ~(size_t)255;
        char* p = ws + off;
        off += bytes;
        return p;
    };
    int* bcnt    = (int*)alloc((size_t)NBUK * 4);
    int* bcur    = (int*)alloc((size_t)NBUK * 4);
    size_t zero_span = (size_t)((char*)(bcur + NBUK) - (char*)bcnt);
    int* bbase   = (int*)alloc((size_t)(NBUK + 1) * 4);
    int* row_ofs = (int*)alloc((size_t)(N + 1) * 4);
    unsigned* staging = (unsigned*)alloc((size_t)E * 4);
    int* csr     = (int*)alloc((size_t)E * 4);
    unsigned short* xb    = (unsigned short*)alloc((size_t)N * IN_CH * 2);
    unsigned short* mean1 = (unsigned short*)alloc((size_t)N * IN_CH * 2);
    unsigned short* h1    = (unsigned short*)alloc((size_t)N * HID * 2);
    unsigned short* mean2 = (unsigned short*)alloc((size_t)N * HID * 2);
    unsigned short* h2    = xb;  // xb+mean1 contiguous span reused for h2 [N,256]
    unsigned char*  x8    = (unsigned char*)alloc((size_t)N * IN_CH);
    unsigned char*  h1f8  = (unsigned char*)alloc((size_t)N * HID);
    unsigned short* W1T   = (unsigned short*)alloc((size_t)HID * (IN_CH + IN_CH) * 2);
    unsigned short* W2T   = (unsigned short*)alloc((size_t)HID * (HID + HID) * 2);
    float* pooled = (float*)alloc((size_t)G * HID * 4);
    float* hidden = (float*)alloc((size_t)G * HID * 4);
    (void)ws_size;

    hipMemsetAsync(bcnt, 0, zero_span, stream);

    const int EB = (E + CHUNK - 1) / CHUNK;  // 196
    bucket_count_k<<<EB, 256, 0, stream>>>(dst, bcnt, E);
    scan1_k<<<1, 256, 0, stream>>>(bcnt, bbase, NBUK, bbase + NBUK);
    bin_scatter_k<<<EB, 256, 0, stream>>>(src, dst, bbase, bcur, staging, E);
    csr_build_k<<<NBUK, 256, 0, stream>>>(staging, bbase, row_ofs, csr);

    // fused prep: W1T + W2T + (xb, x8)
    const int PREP_B = 768 + (int)(((size_t)N * IN_CH / 8 + 255) / 256);
    prep_k<<<PREP_B, 256, 0, stream>>>(W1l, W1r, W1T, W2l, W2r, W2T, x, xb, x8);

    const int MB = (N + 127) / 128;

    // layer 1: mean1 = mean-agg(x8) [fp8 gather]
    //          h1 = relu([mean1|xb] @ W1T^T + b1)  (epilogue also emits h1f8)
    agg_f8_k<IN_CH><<<(N + 3) / 4, 256, 0, stream>>>(x8, row_ofs, csr, mean1, N);
    mfma_gemm_k<<<dim3(MB, HID / 128), 256, 0, stream>>>(
        mean1, IN_CH, xb, IN_CH, W1T, b1, N, HID, h1, h1f8, 1, 1);

    // layer 2: mean2 = mean-agg(h1f8) [fp8 gather]; h2 = relu([mean2|h1] @ W2T^T + b2)
    agg_f8_k<HID><<<(N + 3) / 4, 256, 0, stream>>>(h1f8, row_ofs, csr, mean2, N);
    mfma_gemm_k<<<dim3(MB, HID / 128), 256, 0, stream>>>(
        mean2, HID, h1, HID, W2T, b2, N, HID, h2, nullptr, 1, 1);

    // global mean pool (bf16 in, fp32 out); graph bounds via in-wave binary search
    pool_mean_k<<<(G + 3) / 4, 256, 0, stream>>>(h2, batch, pooled, G, N);

    // MLP head (fp32), full-device grids
    head_gemm_k<<<dim3(G / 32, HID / 32), 256, 0, stream>>>(
        pooled, W3, b3, hidden, G, HID, HID, 1);
    head_gemm_k<<<dim3(G / 32, OUT_CH / 32), 256, 0, stream>>>(
        hidden, W4, b4, out, G, OUT_CH, HID, 0);
}

// Round 9
// 494.831 us; speedup vs baseline: 1.0386x; 1.0386x over previous
//
#include <hip/hip_runtime.h>

#define N_NODES 100000
#define N_EDGES 1600000
#define IN_CH 128
#define HID 256
#define OUT_CH 128
#define N_GRAPHS 2048

#define NBUK 391          // ceil(N_NODES / 256)
#define CHUNK 8192        // edges per binning block

typedef __attribute__((ext_vector_type(8))) short bf16x8;
typedef __attribute__((ext_vector_type(4))) float f32x4;
typedef __attribute__((ext_vector_type(2))) float f32x2;

__device__ inline unsigned short f2b(float f) {  // RNE fp32 -> bf16
    unsigned int u = __builtin_bit_cast(unsigned int, f);
    u = (u + 0x7FFF + ((u >> 16) & 1)) >> 16;
    return (unsigned short)u;
}
__device__ inline float b2f(unsigned short h) {
    unsigned int u = (unsigned int)h << 16;
    return __builtin_bit_cast(float, u);
}

// async global->LDS, 16 B per lane; dst is wave-uniform base, HW adds lane*16
#define GLOAD_LDS16(gsrc, ldst)                                                   \
    __builtin_amdgcn_global_load_lds(                                             \
        (const __attribute__((address_space(1))) void*)(gsrc),                    \
        (__attribute__((address_space(3))) void*)(ldst), 16, 0, 0)

// ---------------------------------------------------------------- scan (bucket bases)
// NBUK=391 fits one 256x8 tile; also writes grand total to *total.
#define SCAN_ITEMS 8
#define SCAN_TILE (256 * SCAN_ITEMS)

__global__ void scan1_k(const int* __restrict__ in, int* __restrict__ out,
                        int n, int* __restrict__ total) {
    __shared__ int wsum[4];
    int base = blockIdx.x * SCAN_TILE + (int)threadIdx.x * SCAN_ITEMS;
    int v[SCAN_ITEMS];
    int s = 0;
    #pragma unroll
    for (int i = 0; i < SCAN_ITEMS; ++i) {
        v[i] = (base + i < n) ? in[base + i] : 0;
        s += v[i];
    }
    int lane = threadIdx.x & 63, wid = threadIdx.x >> 6;
    int incl = s;
    #pragma unroll
    for (int off = 1; off < 64; off <<= 1) {
        int t = __shfl_up(incl, off, 64);
        if (lane >= off) incl += t;
    }
    if (lane == 63) wsum[wid] = incl;
    __syncthreads();
    int wprefix = 0;
    #pragma unroll
    for (int w = 0; w < 4; ++w)
        if (w < wid) wprefix += wsum[w];
    int run = wprefix + incl - s;
    #pragma unroll
    for (int i = 0; i < SCAN_ITEMS; ++i) {
        if (base + i < n) out[base + i] = run;
        run += v[i];
    }
    if (threadIdx.x == 255) *total = wprefix + incl;
}

// staging entry packs src (17 bits, N<2^17) << 8 | (dst & 255): 4 B instead of 8.
__global__ void bin_scatter_k(const int* __restrict__ src, const int* __restrict__ dst,
                              const int* __restrict__ bbase, int* __restrict__ bcur,
                              unsigned* __restrict__ staging, int E) {
    __shared__ int cnt[NBUK];
    __shared__ int gbase[NBUK];
    int tid = threadIdx.x;
    for (int i = tid; i < NBUK; i += 256) cnt[i] = 0;
    __syncthreads();
    int e0 = blockIdx.x * CHUNK;
    int eend = min(e0 + CHUNK, E);
    for (int e = e0 + tid; e < eend; e += 256)
        atomicAdd(&cnt[dst[e] >> 8], 1);
    __syncthreads();
    for (int i = tid; i < NBUK; i += 256) {
        int c = cnt[i];
        gbase[i] = c ? (bbase[i] + atomicAdd(&bcur[i], c)) : 0;
        cnt[i] = 0;  // reuse as local cursor
    }
    __syncthreads();
    for (int e = e0 + tid; e < eend; e += 256) {
        int d = dst[e];
        int b = d >> 8;
        int l = atomicAdd(&cnt[b], 1);
        staging[(size_t)gbase[b] + l] = ((unsigned)src[e] << 8) | (unsigned)(d & 255);
    }
}

__global__ void csr_build_k(const unsigned* __restrict__ staging, const int* __restrict__ bbase,
                            int* __restrict__ row_ofs, int* __restrict__ csr) {
    __shared__ int ldeg[256];
    __shared__ int lofs[256];
    __shared__ int wsum[4];
    int b = blockIdx.x, tid = threadIdx.x;
    int base = bbase[b];
    int cnt = bbase[b + 1] - base;
    ldeg[tid] = 0;
    __syncthreads();
    const unsigned* sp = staging + base;
    for (int i = tid; i < cnt; i += 256)
        atomicAdd(&ldeg[sp[i] & 255], 1);
    __syncthreads();
    int v = ldeg[tid];
    int lane = tid & 63, wid = tid >> 6;
    int incl = v;
    #pragma unroll
    for (int off = 1; off < 64; off <<= 1) {
        int t = __shfl_up(incl, off, 64);
        if (lane >= off) incl += t;
    }
    if (lane == 63) wsum[wid] = incl;
    __syncthreads();
    int wprefix = 0;
    #pragma unroll
    for (int w = 0; w < 4; ++w)
        if (w < wid) wprefix += wsum[w];
    int excl = wprefix + incl - v;
    lofs[tid] = excl;
    int node = b * 256 + tid;
    if (node < N_NODES) row_ofs[node] = base + excl;
    if (b == NBUK - 1 && tid == 0) row_ofs[N_NODES] = N_EDGES;
    ldeg[tid] = 0;  // reuse as cursor
    __syncthreads();
    for (int i = tid; i < cnt; i += 256) {
        unsigned p = sp[i];
        int d = (int)(p & 255);
        int pos = atomicAdd(&ldeg[d], 1);
        csr[base + lofs[d] + pos] = (int)(p >> 8);
    }
}

// ---------------------------------------------------------------- fused prep + bucket count
// One launch: W1 concat->bf16 (blocks 0..255), W2 concat->bf16 (256..767),
// x fp32 -> (bf16, fp8) (768..7017), bucket_count (last 196 blocks).
// bucket_count is independent of the converts; alone it ran 196 blocks on 256
// CUs (sub-1-block/CU, latency-bound). Fused, its latency hides under the
// convert blocks' bandwidth work and one dispatch disappears.
#define PREP_F2B8_B 6250   // ceil(N_NODES*IN_CH/8 / 256)
#define PREP_X (768 + PREP_F2B8_B)
#define PREP_EB 196        // ceil(E / CHUNK)

__global__ void prep_k(const float* __restrict__ W1l, const float* __restrict__ W1r,
                       unsigned short* __restrict__ W1T,
                       const float* __restrict__ W2l, const float* __restrict__ W2r,
                       unsigned short* __restrict__ W2T,
                       const float* __restrict__ x, unsigned short* __restrict__ xb,
                       unsigned char* __restrict__ x8,
                       const int* __restrict__ dst, int* __restrict__ bcnt, int E) {
    __shared__ int cnt[NBUK];
    int b = blockIdx.x;
    if (b < 256) {                       // W1T: HID*(2*IN_CH) = 65536 elems
        int idx = b * 256 + (int)threadIdx.x;
        const int KT = 2 * IN_CH;
        int n = idx / KT, k = idx % KT;
        float v = (k < IN_CH) ? W1l[(size_t)k * HID + n] : W1r[(size_t)(k - IN_CH) * HID + n];
        W1T[idx] = f2b(v);
    } else if (b < 768) {                // W2T: HID*(2*HID) = 131072 elems
        int idx = (b - 256) * 256 + (int)threadIdx.x;
        const int KT = 2 * HID;
        int n = idx / KT, k = idx % KT;
        float v = (k < HID) ? W2l[(size_t)k * HID + n] : W2r[(size_t)(k - HID) * HID + n];
        W2T[idx] = f2b(v);
    } else if (b < PREP_X) {             // f2b8 over N*IN_CH/8 groups
        size_t i = (size_t)(b - 768) * 256 + threadIdx.x;
        size_t n8 = (size_t)N_NODES * IN_CH / 8;
        if (i >= n8) return;
        float4 a = ((const float4*)x)[i * 2];
        float4 c = ((const float4*)x)[i * 2 + 1];
        unsigned short ob[8];
        ob[0] = f2b(a.x); ob[1] = f2b(a.y); ob[2] = f2b(a.z); ob[3] = f2b(a.w);
        ob[4] = f2b(c.x); ob[5] = f2b(c.y); ob[6] = f2b(c.z); ob[7] = f2b(c.w);
        ((uint4*)xb)[i] = *(const uint4*)ob;
        int w0 = 0, w1 = 0;
        w0 = __builtin_amdgcn_cvt_pk_fp8_f32(a.x, a.y, w0, false);
        w0 = __builtin_amdgcn_cvt_pk_fp8_f32(a.z, a.w, w0, true);
        w1 = __builtin_amdgcn_cvt_pk_fp8_f32(c.x, c.y, w1, false);
        w1 = __builtin_amdgcn_cvt_pk_fp8_f32(c.z, c.w, w1, true);
        uint2 o8; o8.x = (unsigned int)w0; o8.y = (unsigned int)w1;
        ((uint2*)x8)[i] = o8;
    } else {                             // bucket_count over edge chunk
        int tid = threadIdx.x;
        for (int i = tid; i < NBUK; i += 256) cnt[i] = 0;
        __syncthreads();
        int e0 = (b - PREP_X) * CHUNK;
        int eend = min(e0 + CHUNK, E);
        for (int e = e0 + tid; e < eend; e += 256)
            atomicAdd(&cnt[dst[e] >> 8], 1);
        __syncthreads();
        for (int i = tid; i < NBUK; i += 256)
            if (cnt[i]) atomicAdd(&bcnt[i], cnt[i]);
    }
}

// ---------------------------------------------------------------- mean aggregation
// R6-proven version (R8's latency restructure REGRESSED +18us -> reverted):
// fp8 in [n,C] -> bf16 mean out [n,C]. One wave per node; GL=C/16 lanes x 16B
// per gather, NG=64/GL edge-groups, 2x unroll. Cross-group shfl_xor reduce.
template <int C>
__global__ void agg_f8_k(const unsigned char* __restrict__ X8, const int* __restrict__ row_ofs,
                         const int* __restrict__ csr, unsigned short* __restrict__ out, int n) {
    constexpr int GL = C / 16;
    constexpr int NG = 64 / GL;
    int w = (int)((blockIdx.x * blockDim.x + threadIdx.x) >> 6);
    int lane = threadIdx.x & 63;
    if (w >= n) return;
    int g = lane / GL, il = lane % GL;
    int s = row_ofs[w], e = row_ofs[w + 1];
    float a[16];
    #pragma unroll
    for (int t = 0; t < 16; ++t) a[t] = 0.f;

    int j = s + g;
    for (; j + NG < e; j += 2 * NG) {
        int i0 = csr[j], i1 = csr[j + NG];
        uint4 r0 = *(const uint4*)&X8[(size_t)i0 * C + il * 16];
        uint4 r1 = *(const uint4*)&X8[(size_t)i1 * C + il * 16];
        const unsigned int* q0 = (const unsigned int*)&r0;
        const unsigned int* q1 = (const unsigned int*)&r1;
        #pragma unroll
        for (int t = 0; t < 4; ++t) {
            f32x2 lo = __builtin_amdgcn_cvt_pk_f32_fp8(q0[t], false);
            f32x2 hi = __builtin_amdgcn_cvt_pk_f32_fp8(q0[t], true);
            a[t * 4 + 0] += lo.x; a[t * 4 + 1] += lo.y;
            a[t * 4 + 2] += hi.x; a[t * 4 + 3] += hi.y;
        }
        #pragma unroll
        for (int t = 0; t < 4; ++t) {
            f32x2 lo = __builtin_amdgcn_cvt_pk_f32_fp8(q1[t], false);
            f32x2 hi = __builtin_amdgcn_cvt_pk_f32_fp8(q1[t], true);
            a[t * 4 + 0] += lo.x; a[t * 4 + 1] += lo.y;
            a[t * 4 + 2] += hi.x; a[t * 4 + 3] += hi.y;
        }
    }
    if (j < e) {
        int i0 = csr[j];
        uint4 r0 = *(const uint4*)&X8[(size_t)i0 * C + il * 16];
        const unsigned int* q0 = (const unsigned int*)&r0;
        #pragma unroll
        for (int t = 0; t < 4; ++t) {
            f32x2 lo = __builtin_amdgcn_cvt_pk_f32_fp8(q0[t], false);
            f32x2 hi = __builtin_amdgcn_cvt_pk_f32_fp8(q0[t], true);
            a[t * 4 + 0] += lo.x; a[t * 4 + 1] += lo.y;
            a[t * 4 + 2] += hi.x; a[t * 4 + 3] += hi.y;
        }
    }

    #pragma unroll
    for (int m = GL; m < 64; m <<= 1)
        #pragma unroll
        for (int t = 0; t < 16; ++t) a[t] += __shfl_xor(a[t], m, 64);

    if (g == 0) {
        float inv = 1.0f / (float)max(e - s, 1);
        uint4 o0, o1;
        unsigned short* p0 = (unsigned short*)&o0;
        unsigned short* p1 = (unsigned short*)&o1;
        #pragma unroll
        for (int t = 0; t < 8; ++t) p0[t] = f2b(a[t] * inv);
        #pragma unroll
        for (int t = 0; t < 8; ++t) p1[t] = f2b(a[8 + t] * inv);
        *(uint4*)&out[(size_t)w * C + il * 16] = o0;
        *(uint4*)&out[(size_t)w * C + il * 16 + 8] = o1;
    }
}

// pool: bf16 input [N,256] -> fp32 pooled [G,256]; one wave per graph.
// Graph bounds via in-wave binary search on batch; row loop unrolled x4.
__global__ void pool_mean_k(const unsigned short* __restrict__ H, const int* __restrict__ batch,
                            float* __restrict__ pooled, int G, int n) {
    int g = (int)((blockIdx.x * blockDim.x + threadIdx.x) >> 6);
    int lane = threadIdx.x & 63;
    if (g >= G) return;
    int lo = 0, hi = n;
    while (lo < hi) { int mid = (lo + hi) >> 1; if (batch[mid] < g) lo = mid + 1; else hi = mid; }
    int s = lo;
    hi = n;
    while (lo < hi) { int mid = (lo + hi) >> 1; if (batch[mid] < g + 1) lo = mid + 1; else hi = mid; }
    int e = lo;

    float a0 = 0.f, a1 = 0.f, a2 = 0.f, a3 = 0.f;
    float b0 = 0.f, b1 = 0.f, b2 = 0.f, b3 = 0.f;
    int r = s;
    for (; r + 4 <= e; r += 4) {
        ushort4 t0 = ((const ushort4*)(H + (size_t)(r + 0) * HID))[lane];
        ushort4 t1 = ((const ushort4*)(H + (size_t)(r + 1) * HID))[lane];
        ushort4 t2 = ((const ushort4*)(H + (size_t)(r + 2) * HID))[lane];
        ushort4 t3 = ((const ushort4*)(H + (size_t)(r + 3) * HID))[lane];
        a0 += b2f(t0.x); a1 += b2f(t0.y); a2 += b2f(t0.z); a3 += b2f(t0.w);
        b0 += b2f(t1.x); b1 += b2f(t1.y); b2 += b2f(t1.z); b3 += b2f(t1.w);
        a0 += b2f(t2.x); a1 += b2f(t2.y); a2 += b2f(t2.z); a3 += b2f(t2.w);
        b0 += b2f(t3.x); b1 += b2f(t3.y); b2 += b2f(t3.z); b3 += b2f(t3.w);
    }
    for (; r < e; ++r) {
        ushort4 t = ((const ushort4*)(H + (size_t)r * HID))[lane];
        a0 += b2f(t.x); a1 += b2f(t.y); a2 += b2f(t.z); a3 += b2f(t.w);
    }
    float inv = 1.0f / (float)max(e - s, 1);
    float4 o; o.x = (a0 + b0) * inv; o.y = (a1 + b1) * inv;
    o.z = (a2 + b2) * inv; o.w = (a3 + b3) * inv;
    ((float4*)(pooled + (size_t)g * HID))[lane] = o;
}

// ---------------------------------------------------------------- bf16 MFMA GEMM
// R1-proven config (fastest passing), FROZEN: 128x128 tile, 4 waves 2x2, BK=32,
// triple-buffered LDS (depth-2 prefetch, steady-state vmcnt(8)), 48 KB LDS.
// R2/R3/R4: bigger tiles, finer interleave, 0-conflict swizzle, fp8 operands all
// neutral-or-worse on this skinny shape (N=256) -- plateau is structural.
__launch_bounds__(256)
__global__ void mfma_gemm_k(const unsigned short* __restrict__ A1, int K1,
                            const unsigned short* __restrict__ A2, int K2,
                            const unsigned short* __restrict__ Bt,
                            const float* __restrict__ bias, int M, int Nfull,
                            void* __restrict__ Cptr, unsigned char* __restrict__ f8out,
                            int c_bf16, int do_relu) {
    __shared__ short ldsA[3 * 4096];
    __shared__ short ldsB[3 * 4096];
    int tid = threadIdx.x, lane = tid & 63;
    int wid = tid >> 6, wm = wid >> 1, wn = wid & 1;
    int row0 = blockIdx.x * 128, col0 = blockIdx.y * 128;
    int q = lane >> 4, l15 = lane & 15;
    int KT = K1 + K2;
    int nk = KT / 32;

    int rr = tid >> 2;                       // 0..63 row within half-tile
    int c8 = ((tid & 3) ^ (rr & 3)) * 8;     // swizzled source k-chunk (shorts)
    int dof = wid * 512;                     // wave-uniform LDS base (shorts) per half

    auto stage = [&](int t, short* bA, short* bB) {
        int kt = t * 32;
        const unsigned short* Asrc; int kk, Ks;
        if (kt < K1) { Asrc = A1; kk = kt; Ks = K1; }
        else         { Asrc = A2; kk = kt - K1; Ks = K2; }
        #pragma unroll
        for (int h = 0; h < 2; ++h) {
            int r = h * 64 + rr;
            int gr = min(row0 + r, M - 1);
            GLOAD_LDS16(Asrc + (size_t)gr * Ks + kk + c8, bA + h * 2048 + dof);
            GLOAD_LDS16(Bt + (size_t)(col0 + r) * KT + kt + c8, bB + h * 2048 + dof);
        }
    };

    f32x4 acc[4][4] = {};

    stage(0, ldsA, ldsB);                    // nk >= 8 always
    stage(1, ldsA + 4096, ldsB + 4096);
    stage(2, ldsA + 8192, ldsB + 8192);

    int bi = 0;
    for (int t = 0; t < nk; ++t) {
        if (t + 2 < nk)      asm volatile("s_waitcnt vmcnt(8)" ::: "memory");
        else if (t + 1 < nk) asm volatile("s_waitcnt vmcnt(4)" ::: "memory");
        else                 asm volatile("s_waitcnt vmcnt(0)" ::: "memory");
        asm volatile("s_barrier" ::: "memory");   // tile t visible to all waves

        short* bA = ldsA + bi * 4096;
        short* bB = ldsB + bi * 4096;
        bf16x8 af[4], bfr[4];
        #pragma unroll
        for (int i = 0; i < 4; ++i) {
            int r = wm * 64 + i * 16 + l15;
            af[i] = *(const bf16x8*)&bA[r * 32 + (q ^ (r & 3)) * 8];
        }
        #pragma unroll
        for (int j = 0; j < 4; ++j) {
            int r = wn * 64 + j * 16 + l15;
            bfr[j] = *(const bf16x8*)&bB[r * 32 + (q ^ (r & 3)) * 8];
        }
        #pragma unroll
        for (int i = 0; i < 4; ++i)
            #pragma unroll
            for (int j = 0; j < 4; ++j)
                acc[i][j] = __builtin_amdgcn_mfma_f32_16x16x32_bf16(af[i], bfr[j], acc[i][j], 0, 0, 0);

        asm volatile("s_barrier" ::: "memory");   // all waves done reading buf bi
        if (t + 3 < nk) stage(t + 3, bA, bB);     // refill buffer just consumed
        bi = (bi == 2) ? 0 : bi + 1;
    }

    // epilogue: D layout col=lane&15, row=quad*4+reg
    #pragma unroll
    for (int i = 0; i < 4; ++i) {
        #pragma unroll
        for (int reg = 0; reg < 4; ++reg) {
            int r = row0 + wm * 64 + i * 16 + q * 4 + reg;
            if (r < M) {
                #pragma unroll
                for (int j = 0; j < 4; ++j) {
                    int cc = col0 + wn * 64 + j * 16 + l15;
                    float v = acc[i][j][reg] + bias[cc];
                    if (do_relu) v = fmaxf(v, 0.f);
                    if (c_bf16) ((unsigned short*)Cptr)[(size_t)r * Nfull + cc] = f2b(v);
                    else        ((float*)Cptr)[(size_t)r * Nfull + cc] = v;
                    if (f8out) {
                        int w8 = __builtin_amdgcn_cvt_pk_fp8_f32(v, v, 0, false);
                        f8out[(size_t)r * Nfull + cc] = (unsigned char)(w8 & 0xFF);
                    }
                }
            }
        }
    }
}

// ---------------------------------------------------------------- fp32 head GEMM
// 32x32 tile per block, 256 thr, each thread a 2x2 micro-tile; K multiple of 16.
__global__ void head_gemm_k(const float* __restrict__ A, const float* __restrict__ B,
                            const float* __restrict__ bias, float* __restrict__ C,
                            int M, int N, int K, int do_relu) {
    __shared__ float As[16][33];
    __shared__ float Bs[16][33];
    int tid = threadIdx.x;
    int row0 = blockIdx.x * 32, col0 = blockIdx.y * 32;
    int tx = tid & 15, ty = tid >> 4;       // 16x16 threads of 2x2 outs
    float a00 = 0.f, a01 = 0.f, a10 = 0.f, a11 = 0.f;

    for (int kt = 0; kt < K; kt += 16) {
        if (tid < 128) {                    // A tile 32x16
            int r = tid >> 2, kc = (tid & 3) * 4;
            float4 v = *(const float4*)(A + (size_t)(row0 + r) * K + kt + kc);
            As[kc + 0][r] = v.x; As[kc + 1][r] = v.y;
            As[kc + 2][r] = v.z; As[kc + 3][r] = v.w;
        } else {                            // B tile 16x32
            int t2 = tid - 128;
            int kr = t2 >> 3, c4 = (t2 & 7) * 4;
            float4 v = *(const float4*)(B + (size_t)(kt + kr) * N + col0 + c4);
            *(float4*)&Bs[kr][c4] = v;
        }
        __syncthreads();
        #pragma unroll
        for (int k = 0; k < 16; ++k) {
            float x0 = As[k][ty * 2], x1 = As[k][ty * 2 + 1];
            float y0 = Bs[k][tx * 2], y1 = Bs[k][tx * 2 + 1];
            a00 = fmaf(x0, y0, a00); a01 = fmaf(x0, y1, a01);
            a10 = fmaf(x1, y0, a10); a11 = fmaf(x1, y1, a11);
        }
        __syncthreads();
    }

    int r0 = row0 + ty * 2, c0 = col0 + tx * 2;
    float bv0 = bias[c0], bv1 = bias[c0 + 1];
    float o00 = a00 + bv0, o01 = a01 + bv1, o10 = a10 + bv0, o11 = a11 + bv1;
    if (do_relu) {
        o00 = fmaxf(o00, 0.f); o01 = fmaxf(o01, 0.f);
        o10 = fmaxf(o10, 0.f); o11 = fmaxf(o11, 0.f);
    }
    C[(size_t)r0 * N + c0] = o00;       C[(size_t)r0 * N + c0 + 1] = o01;
    C[(size_t)(r0 + 1) * N + c0] = o10; C[(size_t)(r0 + 1) * N + c0 + 1] = o11;
}

// ---------------------------------------------------------------- launcher
extern "C" void kernel_launch(void* const* d_in, const int* in_sizes, int n_in,
                              void* d_out, int out_size, void* d_ws, size_t ws_size,
                              hipStream_t stream) {
    const float* x    = (const float*)d_in[0];
    const int*   ei   = (const int*)d_in[1];
    const int*   batch= (const int*)d_in[2];
    const float* W1l  = (const float*)d_in[3];
    const float* b1   = (const float*)d_in[4];
    const float* W1r  = (const float*)d_in[5];
    const float* W2l  = (const float*)d_in[6];
    const float* b2   = (const float*)d_in[7];
    const float* W2r  = (const float*)d_in[8];
    const float* W3   = (const float*)d_in[9];
    const float* b3   = (const float*)d_in[10];
    const float* W4   = (const float*)d_in[11];
    const float* b4   = (const float*)d_in[12];
    float* out = (float*)d_out;

    const int N = N_NODES, E = N_EDGES, G = N_GRAPHS;
    const int* src = ei;
    const int* dst = ei + E;

    char* ws = (char*)d_ws;
    size_t off = 0;
    auto alloc = [&](size_t bytes) -> char* {
        off = (off + 255) & ~(size_t)255;
        char* p = ws + off;
        off += bytes;
        return p;
    };
    int* bcnt    = (int*)alloc((size_t)NBUK * 4);
    int* bcur    = (int*)alloc((size_t)NBUK * 4);
    size_t zero_span = (size_t)((char*)(bcur + NBUK) - (char*)bcnt);
    int* bbase   = (int*)alloc((size_t)(NBUK + 1) * 4);
    int* row_ofs = (int*)alloc((size_t)(N + 1) * 4);
    unsigned* staging = (unsigned*)alloc((size_t)E * 4);
    int* csr     = (int*)alloc((size_t)E * 4);
    unsigned short* xb    = (unsigned short*)alloc((size_t)N * IN_CH * 2);
    unsigned short* mean1 = (unsigned short*)alloc((size_t)N * IN_CH * 2);
    unsigned short* h1    = (unsigned short*)alloc((size_t)N * HID * 2);
    unsigned short* mean2 = (unsigned short*)alloc((size_t)N * HID * 2);
    unsigned short* h2    = xb;  // xb+mean1 contiguous span reused for h2 [N,256]
    unsigned char*  x8    = (unsigned char*)alloc((size_t)N * IN_CH);
    unsigned char*  h1f8  = (unsigned char*)alloc((size_t)N * HID);
    unsigned short* W1T   = (unsigned short*)alloc((size_t)HID * (IN_CH + IN_CH) * 2);
    unsigned short* W2T   = (unsigned short*)alloc((size_t)HID * (HID + HID) * 2);
    float* pooled = (float*)alloc((size_t)G * HID * 4);
    float* hidden = (float*)alloc((size_t)G * HID * 4);
    (void)ws_size;

    hipMemsetAsync(bcnt, 0, zero_span, stream);

    // fused prep: W1T + W2T + (xb, x8) + bucket_count (last PREP_EB blocks)
    prep_k<<<PREP_X + PREP_EB, 256, 0, stream>>>(
        W1l, W1r, W1T, W2l, W2r, W2T, x, xb, x8, dst, bcnt, E);

    scan1_k<<<1, 256, 0, stream>>>(bcnt, bbase, NBUK, bbase + NBUK);
    bin_scatter_k<<<PREP_EB, 256, 0, stream>>>(src, dst, bbase, bcur, staging, E);
    csr_build_k<<<NBUK, 256, 0, stream>>>(staging, bbase, row_ofs, csr);

    const int MB = (N + 127) / 128;

    // layer 1: mean1 = mean-agg(x8) [fp8 gather]
    //          h1 = relu([mean1|xb] @ W1T^T + b1)  (epilogue also emits h1f8)
    agg_f8_k<IN_CH><<<(N + 3) / 4, 256, 0, stream>>>(x8, row_ofs, csr, mean1, N);
    mfma_gemm_k<<<dim3(MB, HID / 128), 256, 0, stream>>>(
        mean1, IN_CH, xb, IN_CH, W1T, b1, N, HID, h1, h1f8, 1, 1);

    // layer 2: mean2 = mean-agg(h1f8) [fp8 gather]; h2 = relu([mean2|h1] @ W2T^T + b2)
    agg_f8_k<HID><<<(N + 3) / 4, 256, 0, stream>>>(h1f8, row_ofs, csr, mean2, N);
    mfma_gemm_k<<<dim3(MB, HID / 128), 256, 0, stream>>>(
        mean2, HID, h1, HID, W2T, b2, N, HID, h2, nullptr, 1, 1);

    // global mean pool (bf16 in, fp32 out); graph bounds via in-wave binary search
    pool_mean_k<<<(G + 3) / 4, 256, 0, stream>>>(h2, batch, pooled, G, N);

    // MLP head (fp32), full-device grids
    head_gemm_k<<<dim3(G / 32, HID / 32), 256, 0, stream>>>(
        pooled, W3, b3, hidden, G, HID, HID, 1);
    head_gemm_k<<<dim3(G / 32, OUT_CH / 32), 256, 0, stream>>>(
        hidden, W4, b4, out, G, OUT_CH, HID, 0);
}